// Round 7
// baseline (1899.147 us; speedup 1.0000x reference)
//
#include <hip/hip_runtime.h>

#define EMD 0.77880078307140486824  // exp(-1/4)
#define ESD 0.36787944117144232160  // exp(-1)
#define TCG 256                     // g1/iir2 chunk (2 chunks of 512)
#define TCS 128                     // downstream sub-chunk

// ---------------------------------------------------------------------------
// g1_fused: per (b, f-tile, t-tile 128): mu row f and lv row 500+f, K=784.
// LDS operands staged as f32 (exact); converted to f64 in registers.
// Micro-tile 4m x 8t; FMA chain per output: k ascending (bit-identical).
// sample = relu(mu)+eps*exp(0.5*relu(lv)) -> SAMP (b,f,tt) chunk-local (TCG).
// ---------------------------------------------------------------------------
__global__ __launch_bounds__(256) void g1_fused(
    const float* __restrict__ X,    // (64,784,512)
    const float* __restrict__ W1,   // (1000,784)
    const float* __restrict__ B1,   // (1000)
    const float* __restrict__ EPS,  // (64,500,512)
    double* __restrict__ SAMP,      // (64,500,TCG)
    int t0)
{
    const int b   = blockIdx.z;
    const int m0  = blockIdx.y * 64;
    const int tt0 = blockIdx.x * 128;   // 0 or 128 within TCG chunk
    const int tg  = t0 + tt0;

    __shared__ float Am[16][68];
    __shared__ float Al[16][68];
    __shared__ float Bs[16][132];

    const int tid = threadIdx.x;
    const int tx = tid & 15;       // t dir: cols {2tx,2tx+1}+{0,32,64,96}
    const int ty = tid >> 4;       // m dir: rows {2ty,2ty+1,2ty+32,2ty+33}

    double am[4][8] = {};
    double al[4][8] = {};

    for (int k0 = 0; k0 < 784; k0 += 16) {
        {   // stage A (mu + lv): 64 m x 16 k, f32
            const int m  = tid >> 2;
            const int kk = (tid & 3) * 4;
            int f = m0 + m; if (f > 499) f = 499;
            const float4 aw = *(const float4*)&W1[(size_t)f * 784 + k0 + kk];
            Am[kk+0][m] = aw.x; Am[kk+1][m] = aw.y;
            Am[kk+2][m] = aw.z; Am[kk+3][m] = aw.w;
            const float4 lw = *(const float4*)&W1[(size_t)(500 + f) * 784 + k0 + kk];
            Al[kk+0][m] = lw.x; Al[kk+1][m] = lw.y;
            Al[kk+2][m] = lw.z; Al[kk+3][m] = lw.w;
        }
        {   // stage B: 16 k x 128 t, f32
            const int bk = tid >> 4;
            const int bt = (tid & 15) * 8;
            const float* xp = &X[((size_t)b * 784 + k0 + bk) * 512 + tg + bt];
            *(float4*)&Bs[bk][bt]     = *(const float4*)xp;
            *(float4*)&Bs[bk][bt + 4] = *(const float4*)(xp + 4);
        }
        __syncthreads();
        #pragma unroll
        for (int k = 0; k < 16; ++k) {
            double ar[4], lr[4], br[8];
            #pragma unroll
            for (int h = 0; h < 2; ++h) {
                const float2 a2v = *(const float2*)&Am[k][2*ty + 32*h];
                ar[2*h] = (double)a2v.x; ar[2*h+1] = (double)a2v.y;
                const float2 l2v = *(const float2*)&Al[k][2*ty + 32*h];
                lr[2*h] = (double)l2v.x; lr[2*h+1] = (double)l2v.y;
            }
            #pragma unroll
            for (int h = 0; h < 4; ++h) {
                const float2 b2v = *(const float2*)&Bs[k][2*tx + 32*h];
                br[2*h] = (double)b2v.x; br[2*h+1] = (double)b2v.y;
            }
            #pragma unroll
            for (int i = 0; i < 4; ++i)
                #pragma unroll
                for (int j = 0; j < 8; ++j) {
                    am[i][j] = fma(ar[i], br[j], am[i][j]);
                    al[i][j] = fma(lr[i], br[j], al[i][j]);
                }
        }
        __syncthreads();
    }

    const int rows[4] = {2*ty, 2*ty+1, 2*ty+32, 2*ty+33};
    #pragma unroll
    for (int i = 0; i < 4; ++i) {
        const int f = m0 + rows[i];
        if (f >= 500) continue;
        const double bm = (double)B1[f];
        const double bl = (double)B1[500 + f];
        const size_t ebase = ((size_t)b * 500 + f) * 512 + tg;
        const size_t obase = ((size_t)b * 500 + f) * TCG + tt0;
        #pragma unroll
        for (int j = 0; j < 8; ++j) {
            const int c = 2*tx + (j >> 1) * 32 + (j & 1);
            const double mu = fmax(am[i][j] + bm, 0.0);
            const double lv = fmax(al[i][j] + bl, 0.0);
            const double e  = (double)EPS[ebase + c];
            SAMP[obase + c] = mu + e * exp(0.5 * lv);
        }
    }
}

// ---------------------------------------------------------------------------
// iir2: exact sequential dual-exp, in-place on (32000 rows, TCG). 64 rows
// per block, 64-col LDS sub-tiles; (m,s) carried across chunks.
// ---------------------------------------------------------------------------
__global__ __launch_bounds__(256) void iir2_chunk(
    double* __restrict__ A,
    double* __restrict__ stM, double* __restrict__ stS, int first)
{
    __shared__ double tile[64][65];
    const int tid = threadIdx.x;
    const int r0 = blockIdx.x * 64;
    double m = 0.0, s = 0.0;
    if (tid < 64 && !first) { m = stM[r0 + tid]; s = stS[r0 + tid]; }

    for (int sub = 0; sub < TCG / 64; ++sub) {
        #pragma unroll
        for (int q = 0; q < 8; ++q) {
            const int e2 = q * 256 + tid;
            const int r = e2 >> 5;
            const int c = (e2 & 31) * 2;
            const double2 v = *(const double2*)&A[(size_t)(r0 + r) * TCG + sub * 64 + c];
            tile[r][c] = v.x; tile[r][c + 1] = v.y;
        }
        __syncthreads();
        if (tid < 64) {
            #pragma unroll
            for (int c = 0; c < 64; ++c) {
                const double x = tile[tid][c];
                m = EMD * m + x;
                s = ESD * s + x;
                tile[tid][c] = m - s;
            }
        }
        __syncthreads();
        #pragma unroll
        for (int q = 0; q < 8; ++q) {
            const int e2 = q * 256 + tid;
            const int r = e2 >> 5;
            const int c = (e2 & 31) * 2;
            double2 v; v.x = tile[r][c]; v.y = tile[r][c + 1];
            *(double2*)&A[(size_t)(r0 + r) * TCG + sub * 64 + c] = v;
        }
        __syncthreads();
    }
    if (tid < 64) { stM[r0 + tid] = m; stS[r0 + tid] = s; }
}

// ---------------------------------------------------------------------------
// g2: wx2[tl,b,o] = sum_f a2[b,f,t_off+tl]*W2[o,f] + B2[o]; K=500 pad 512.
// A kept f64 in LDS; W2 staged f32 (exact). Micro 4tl x 8o.
// ---------------------------------------------------------------------------
__global__ __launch_bounds__(256) void g2_chunk(
    const double* __restrict__ A2,  // (64,500,TCG)
    const float* __restrict__ W2,   // (500,500)
    const float* __restrict__ B2,   // (500)
    double* __restrict__ WX2,       // (TCS,64,500)
    int t_off)
{
    const int b   = blockIdx.z;
    const int o0  = blockIdx.y * 128;
    const int tl0 = blockIdx.x * 64;

    __shared__ double At[16][66];
    __shared__ float  Wo[16][132];

    const int tid = threadIdx.x;
    const int tx = tid & 15;   // o dir
    const int ty = tid >> 4;   // tl dir

    double acc[4][8] = {};

    for (int k0 = 0; k0 < 512; k0 += 16) {
        {   // stage A: 16 f x 64 tl (f64)
            const int kk = tid >> 4;
            const int t4 = (tid & 15) * 4;
            const int f = k0 + kk;
            if (f < 500) {
                const double2 v0 = *(const double2*)&A2[((size_t)b * 500 + f) * TCG + t_off + tl0 + t4];
                const double2 v1 = *(const double2*)&A2[((size_t)b * 500 + f) * TCG + t_off + tl0 + t4 + 2];
                At[kk][t4+0] = v0.x; At[kk][t4+1] = v0.y;
                At[kk][t4+2] = v1.x; At[kk][t4+3] = v1.y;
            } else {
                At[kk][t4+0] = 0.0; At[kk][t4+1] = 0.0;
                At[kk][t4+2] = 0.0; At[kk][t4+3] = 0.0;
            }
        }
        {   // stage W: 16 f x 128 o (f32)
            const int oo = tid & 127;
            const int fc = (tid >> 7) * 8;
            int o = o0 + oo; if (o > 499) o = 499;
            const float* wp = &W2[(size_t)o * 500 + k0 + fc];
            if (k0 + fc + 7 < 500) {
                const float4 w0 = *(const float4*)wp;
                const float4 w1 = *(const float4*)(wp + 4);
                Wo[fc+0][oo] = w0.x; Wo[fc+1][oo] = w0.y;
                Wo[fc+2][oo] = w0.z; Wo[fc+3][oo] = w0.w;
                Wo[fc+4][oo] = w1.x; Wo[fc+5][oo] = w1.y;
                Wo[fc+6][oo] = w1.z; Wo[fc+7][oo] = w1.w;
            } else {
                #pragma unroll
                for (int c = 0; c < 8; ++c)
                    Wo[fc+c][oo] = (k0 + fc + c < 500) ? wp[c] : 0.0f;
            }
        }
        __syncthreads();
        #pragma unroll
        for (int k = 0; k < 16; ++k) {
            double ar[4], br[8];
            #pragma unroll
            for (int h = 0; h < 2; ++h) {
                const double2 a2v = *(const double2*)&At[k][2*ty + 32*h];
                ar[2*h] = a2v.x; ar[2*h+1] = a2v.y;
            }
            #pragma unroll
            for (int h = 0; h < 4; ++h) {
                const float2 w2v = *(const float2*)&Wo[k][2*tx + 32*h];
                br[2*h] = (double)w2v.x; br[2*h+1] = (double)w2v.y;
            }
            #pragma unroll
            for (int i = 0; i < 4; ++i)
                #pragma unroll
                for (int j = 0; j < 8; ++j)
                    acc[i][j] = fma(ar[i], br[j], acc[i][j]);
        }
        __syncthreads();
    }

    const int rows[4] = {2*ty, 2*ty+1, 2*ty+32, 2*ty+33};
    #pragma unroll
    for (int i = 0; i < 4; ++i) {
        const int tl = tl0 + rows[i];
        #pragma unroll
        for (int j = 0; j < 8; ++j) {
            const int o = o0 + 2*tx + (j >> 1) * 32 + (j & 1);
            if (o < 500)
                WX2[((size_t)tl * 64 + b) * 500 + o] = acc[i][j] + (double)B2[o];
        }
    }
}

// ---------------------------------------------------------------------------
// LIF2 + IIR3 fused, in-place on (TCS, 32000); carries (v, sp, m, s).
// ---------------------------------------------------------------------------
__global__ __launch_bounds__(256) void lif2iir3_chunk(
    double* __restrict__ WX,
    double* __restrict__ stV, double* __restrict__ stSp,
    double* __restrict__ stM, double* __restrict__ stS, int first)
{
    const int idx = blockIdx.x * 256 + threadIdx.x;
    if (idx >= 32000) return;
    double v, sp, m, s;
    if (first) { v = 0.0; sp = 0.0; m = 0.0; s = 0.0; }
    else { v = stV[idx]; sp = stSp[idx]; m = stM[idx]; s = stS[idx]; }
    for (int tt = 0; tt < TCS; ++tt) {
        const double cur = WX[(size_t)tt * 32000 + idx];
        v = EMD * v * (1.0 - sp) + cur;
        sp = (v >= 1.0) ? 1.0 : 0.0;
        m = EMD * m + sp;
        s = ESD * s + sp;
        WX[(size_t)tt * 32000 + idx] = m - s;
    }
    stV[idx] = v; stSp[idx] = sp; stM[idx] = m; stS[idx] = s;
}

// ---------------------------------------------------------------------------
// g3: one wave per R; lanes split K, 10 outputs tree-reduced via shfl_xor.
// ---------------------------------------------------------------------------
__global__ __launch_bounds__(256) void g3_chunk(
    const double* __restrict__ A3,  // (64*TCS, 500)
    const float* __restrict__ W3,   // (10,500)
    const float* __restrict__ B3,   // (10)
    double* __restrict__ WX3)       // (64*TCS, 10)
{
    __shared__ float w3s[5000];
    for (int i = threadIdx.x; i < 5000; i += 256) w3s[i] = W3[i];
    __syncthreads();

    const int lane = threadIdx.x & 63;
    const int R = blockIdx.x * 4 + (threadIdx.x >> 6);   // 0..8191
    const double* row = A3 + (size_t)R * 500;

    double p[10] = {};
    #pragma unroll
    for (int c = 0; c < 8; ++c) {
        const int i = c * 64 + lane;
        const int ii = (i < 500) ? i : 0;
        const double x = (i < 500) ? row[ii] : 0.0;
        #pragma unroll
        for (int o = 0; o < 10; ++o)
            p[o] = fma(x, (double)w3s[o * 500 + ii], p[o]);
    }
    #pragma unroll
    for (int off = 32; off; off >>= 1)
        #pragma unroll
        for (int o = 0; o < 10; ++o)
            p[o] += __shfl_xor(p[o], off, 64);
    if (lane < 10)
        WX3[(size_t)R * 10 + lane] = p[lane] + (double)B3[lane];
}

// ---------------------------------------------------------------------------
// lif3: (tt*640+idx) -> OUT[idx*512 + t0+tt]; carries (v, sp).
// ---------------------------------------------------------------------------
__global__ __launch_bounds__(256) void lif3_chunk(
    const double* __restrict__ WX3, float* __restrict__ OUT,
    double* __restrict__ stV, double* __restrict__ stSp, int first, int t0)
{
    const int idx = blockIdx.x * 256 + threadIdx.x;
    if (idx >= 640) return;
    double v = first ? 0.0 : stV[idx];
    double sp = first ? 0.0 : stSp[idx];
    for (int tt = 0; tt < TCS; ++tt) {
        const double cur = WX3[(size_t)tt * 640 + idx];
        v = EMD * v * (1.0 - sp) + cur;
        sp = (v >= 1.0) ? 1.0 : 0.0;
        OUT[(size_t)idx * 512 + t0 + tt] = (float)sp;
    }
    stV[idx] = v; stSp[idx] = sp;
}

__global__ void sent_kernel(float* __restrict__ OUT, float v) { OUT[0] = v; }

// ---------------------------------------------------------------------------
extern "C" void kernel_launch(void* const* d_in, const int* in_sizes, int n_in,
                              void* d_out, int out_size, void* d_ws, size_t ws_size,
                              hipStream_t stream)
{
    float* OUT = (float*)d_out;

    const int expect[8] = {25690112, 16384000, 784000, 1000, 250000, 500, 5000, 10};
    int bad = -1;
    if (n_in != 8) bad = 0;
    else {
        for (int k = 0; k < 8; ++k)
            if (in_sizes[k] != expect[k]) { bad = 1 + k; break; }
        if (bad < 0 && out_size != 327680) bad = 9;
        if (bad < 0 && ws_size < (size_t)131072000) bad = 10;
    }
    if (bad >= 0) {
        sent_kernel<<<1, 1, 0, stream>>>(OUT, 4100.0f + bad);
        return;
    }

    const float* X   = (const float*)d_in[0];
    const float* EPS = (const float*)d_in[1];
    const float* W1  = (const float*)d_in[2];
    const float* B1  = (const float*)d_in[3];
    const float* W2  = (const float*)d_in[4];
    const float* B2  = (const float*)d_in[5];
    const float* W3  = (const float*)d_in[6];
    const float* B3  = (const float*)d_in[7];

    double* ws = (double*)d_ws;
    double* buf1  = ws;               // (64,500,TCG)  8,192,000 doubles
    double* buf2  = ws + 8192000;     // (TCS,64,500)  4,096,000
    double* buf4  = ws + 12288000;    // (64*TCS,10)      81,920
    double* stM2  = ws + 12400000;    // 32,000 each
    double* stS2  = ws + 12432000;
    double* stV2  = ws + 12464000;
    double* stSp2 = ws + 12496000;
    double* stM3  = ws + 12528000;
    double* stS3  = ws + 12560000;
    double* stV3  = ws + 12592000;    // 640 each
    double* stSp3 = ws + 12593000;

    for (int tc = 0; tc < 512 / TCG; ++tc) {
        const int t0 = tc * TCG;
        const int firstc = (tc == 0) ? 1 : 0;
        g1_fused<<<dim3(2, 8, 64), 256, 0, stream>>>(X, W1, B1, EPS, buf1, t0);
        iir2_chunk<<<500, 256, 0, stream>>>(buf1, stM2, stS2, firstc);
        for (int h = 0; h < TCG / TCS; ++h) {
            const int first = (firstc && h == 0) ? 1 : 0;
            g2_chunk<<<dim3(2, 4, 64), 256, 0, stream>>>(buf1, W2, B2, buf2, h * TCS);
            lif2iir3_chunk<<<125, 256, 0, stream>>>(buf2, stV2, stSp2, stM3, stS3, first);
            g3_chunk<<<2048, 256, 0, stream>>>(buf2, W3, B3, buf4);
            lif3_chunk<<<3, 256, 0, stream>>>(buf4, OUT, stV3, stSp3, first, t0 + h * TCS);
        }
    }
}

// Round 9
// 1681.536 us; speedup vs baseline: 1.1294x; 1.1294x over previous
//
#include <hip/hip_runtime.h>

#define EMD 0.77880078307140486824  // exp(-1/4)
#define ESD 0.36787944117144232160  // exp(-1)
#define TCG 256                     // g1/iir2 chunk (2 chunks of 512)
#define TCS 128                     // downstream sub-chunk

typedef double d4 __attribute__((ext_vector_type(4)));

// ---------------------------------------------------------------------------
// MFMA f64 16x16x4 C/D-layout probe. One wave, exact integer test:
// A[i][k]=100i+k+1 (lane: i=lane&15, k=lane>>4), B[k][j]=1000k+j+7.
// Tests 4 candidate D maps; writes flag 0..3 (4 = none matched).
//   h0: row=4*lk+v, col=lr      h1: row=lk+4*v, col=lr
//   h2: row=lr, col=4*lk+v      h3: row=lr, col=lk+4*v
// ---------------------------------------------------------------------------
__global__ void mfma_probe(double* __restrict__ flagOut)
{
    const int lane = threadIdx.x & 63;
    const int lr = lane & 15;
    const int lk = lane >> 4;
    const double a = 100.0 * lr + lk + 1.0;
    const double b = 1000.0 * lk + lr + 7.0;
    d4 c = {};
    c = __builtin_amdgcn_mfma_f64_16x16x4f64(a, b, c, 0, 0, 0);
    int myflag = 4;
    for (int h = 3; h >= 0; --h) {
        int ok = 1;
        for (int v = 0; v < 4; ++v) {
            int i, j;
            if (h == 0)      { i = 4 * lk + v; j = lr; }
            else if (h == 1) { i = lk + 4 * v; j = lr; }
            else if (h == 2) { i = lr; j = 4 * lk + v; }
            else             { i = lr; j = lk + 4 * v; }
            double e = 0.0;
            for (int k = 0; k < 4; ++k)
                e += (100.0 * i + k + 1.0) * (1000.0 * k + j + 7.0);
            if (c[v] != e) ok = 0;
        }
        if (__all(ok)) myflag = h;
    }
    if (lane == 0) flagOut[0] = (double)myflag;
}

__device__ __forceinline__ void frag_rc(int flag, int lk, int lr, int v,
                                        int& rl, int& cl)
{
    if (flag == 1)      { rl = lk + 4 * v; cl = lr; }
    else if (flag == 2) { rl = lr; cl = 4 * lk + v; }
    else if (flag == 3) { rl = lr; cl = lk + 4 * v; }
    else                { rl = 4 * lk + v; cl = lr; }
}

// ---------------------------------------------------------------------------
// g1_mfma: f64 MFMA GEMM. Block = 4 waves = 64f x 64t; each wave 32f x 32t
// for BOTH mu (rows f) and lv (rows 500+f). K=784 staged 16/iter as f32
// (exact), cvt to f64 per fragment. Epilogue map selected by probe flag.
// ---------------------------------------------------------------------------
__global__ __launch_bounds__(256) void g1_mfma(
    const float* __restrict__ X,    // (64,784,512)
    const float* __restrict__ W1,   // (1000,784)
    const float* __restrict__ B1,   // (1000)
    const float* __restrict__ EPS,  // (64,500,512)
    double* __restrict__ SAMP,      // (64,500,TCG)
    const double* __restrict__ FLG,
    int t0)
{
    const int b   = blockIdx.z;
    const int m0  = blockIdx.y * 64;
    const int tt0 = blockIdx.x * 64;        // within TCG chunk
    const int tg  = t0 + tt0;               // global t base

    __shared__ float Am[16][68];
    __shared__ float Al[16][68];
    __shared__ float Bs[16][68];

    const int tid  = threadIdx.x;
    const int lane = tid & 63;
    const int wid  = tid >> 6;
    const int wf   = (wid >> 1) * 32;       // wave f offset in tile
    const int wt   = (wid & 1) * 32;        // wave t offset in tile
    const int lr   = lane & 15;
    const int lk   = lane >> 4;

    d4 accm[2][2] = {};
    d4 accl[2][2] = {};

    for (int k0 = 0; k0 < 784; k0 += 16) {
        {   // stage A (mu + lv): 64 f x 16 k, f32
            const int m  = tid >> 2;
            const int kk = (tid & 3) * 4;
            int f = m0 + m; if (f > 499) f = 499;
            const float4 aw = *(const float4*)&W1[(size_t)f * 784 + k0 + kk];
            Am[kk+0][m] = aw.x; Am[kk+1][m] = aw.y;
            Am[kk+2][m] = aw.z; Am[kk+3][m] = aw.w;
            const float4 lw = *(const float4*)&W1[(size_t)(500 + f) * 784 + k0 + kk];
            Al[kk+0][m] = lw.x; Al[kk+1][m] = lw.y;
            Al[kk+2][m] = lw.z; Al[kk+3][m] = lw.w;
        }
        {   // stage B: 16 k x 64 t, f32
            const int bk = tid >> 4;
            const int bt = (tid & 15) * 4;
            *(float4*)&Bs[bk][bt] =
                *(const float4*)&X[((size_t)b * 784 + k0 + bk) * 512 + tg + bt];
        }
        __syncthreads();
        #pragma unroll
        for (int ks = 0; ks < 4; ++ks) {
            const int kr = 4 * ks + lk;
            const double a0 = (double)Am[kr][wf + lr];
            const double a1 = (double)Am[kr][wf + 16 + lr];
            const double l0 = (double)Al[kr][wf + lr];
            const double l1 = (double)Al[kr][wf + 16 + lr];
            const double b0 = (double)Bs[kr][wt + lr];
            const double b1 = (double)Bs[kr][wt + 16 + lr];
            accm[0][0] = __builtin_amdgcn_mfma_f64_16x16x4f64(a0, b0, accm[0][0], 0, 0, 0);
            accm[0][1] = __builtin_amdgcn_mfma_f64_16x16x4f64(a0, b1, accm[0][1], 0, 0, 0);
            accm[1][0] = __builtin_amdgcn_mfma_f64_16x16x4f64(a1, b0, accm[1][0], 0, 0, 0);
            accm[1][1] = __builtin_amdgcn_mfma_f64_16x16x4f64(a1, b1, accm[1][1], 0, 0, 0);
            accl[0][0] = __builtin_amdgcn_mfma_f64_16x16x4f64(l0, b0, accl[0][0], 0, 0, 0);
            accl[0][1] = __builtin_amdgcn_mfma_f64_16x16x4f64(l0, b1, accl[0][1], 0, 0, 0);
            accl[1][0] = __builtin_amdgcn_mfma_f64_16x16x4f64(l1, b0, accl[1][0], 0, 0, 0);
            accl[1][1] = __builtin_amdgcn_mfma_f64_16x16x4f64(l1, b1, accl[1][1], 0, 0, 0);
        }
        __syncthreads();
    }

    const int flag = (int)FLG[0];
    for (int fi = 0; fi < 2; ++fi)
    for (int tj = 0; tj < 2; ++tj)
    for (int v = 0; v < 4; ++v) {
        int rl, cl;
        frag_rc(flag, lk, lr, v, rl, cl);
        const int f = m0 + wf + fi * 16 + rl;
        if (f >= 500) continue;
        const int tloc = tt0 + wt + tj * 16 + cl;
        const double bm = (double)B1[f];
        const double bl = (double)B1[500 + f];
        const double mu = fmax(accm[fi][tj][v] + bm, 0.0);
        const double lv = fmax(accl[fi][tj][v] + bl, 0.0);
        const double e  = (double)EPS[((size_t)b * 500 + f) * 512 + t0 + tloc];
        SAMP[((size_t)b * 500 + f) * TCG + tloc] = mu + e * exp(0.5 * lv);
    }
}

// ---------------------------------------------------------------------------
// iir2: exact sequential dual-exp, in-place on (32000 rows, TCG). 64 rows
// per block, 64-col LDS sub-tiles; (m,s) carried across chunks.
// ---------------------------------------------------------------------------
__global__ __launch_bounds__(256) void iir2_chunk(
    double* __restrict__ A,
    double* __restrict__ stM, double* __restrict__ stS, int first)
{
    __shared__ double tile[64][65];
    const int tid = threadIdx.x;
    const int r0 = blockIdx.x * 64;
    double m = 0.0, s = 0.0;
    if (tid < 64 && !first) { m = stM[r0 + tid]; s = stS[r0 + tid]; }

    for (int sub = 0; sub < TCG / 64; ++sub) {
        #pragma unroll
        for (int q = 0; q < 8; ++q) {
            const int e2 = q * 256 + tid;
            const int r = e2 >> 5;
            const int c = (e2 & 31) * 2;
            const double2 v = *(const double2*)&A[(size_t)(r0 + r) * TCG + sub * 64 + c];
            tile[r][c] = v.x; tile[r][c + 1] = v.y;
        }
        __syncthreads();
        if (tid < 64) {
            #pragma unroll
            for (int c = 0; c < 64; ++c) {
                const double x = tile[tid][c];
                m = EMD * m + x;
                s = ESD * s + x;
                tile[tid][c] = m - s;
            }
        }
        __syncthreads();
        #pragma unroll
        for (int q = 0; q < 8; ++q) {
            const int e2 = q * 256 + tid;
            const int r = e2 >> 5;
            const int c = (e2 & 31) * 2;
            double2 v; v.x = tile[r][c]; v.y = tile[r][c + 1];
            *(double2*)&A[(size_t)(r0 + r) * TCG + sub * 64 + c] = v;
        }
        __syncthreads();
    }
    if (tid < 64) { stM[r0 + tid] = m; stS[r0 + tid] = s; }
}

// ---------------------------------------------------------------------------
// g2_mfma: wx2[tl,b,o] = sum_f a2[b,f,t_off+tl]*W2[o,f] + B2[o].
// A = a2 (f64 LDS), B = W2 (f32 LDS, exact). Block 64tl x 64o, 4 waves.
// ---------------------------------------------------------------------------
__global__ __launch_bounds__(256) void g2_mfma(
    const double* __restrict__ A2,  // (64,500,TCG)
    const float* __restrict__ W2,   // (500,500)
    const float* __restrict__ B2,   // (500)
    double* __restrict__ WX2,       // (TCS,64,500)
    const double* __restrict__ FLG,
    int t_off)
{
    const int b   = blockIdx.z;
    const int o0  = blockIdx.y * 64;
    const int tl0 = blockIdx.x * 64;

    __shared__ double At[16][66];
    __shared__ float  Wo[16][68];

    const int tid  = threadIdx.x;
    const int lane = tid & 63;
    const int wid  = tid >> 6;
    const int wtl  = (wid >> 1) * 32;
    const int wo   = (wid & 1) * 32;
    const int lr   = lane & 15;
    const int lk   = lane >> 4;

    d4 acc[2][2] = {};

    for (int k0 = 0; k0 < 512; k0 += 16) {
        {   // stage A: 16 f x 64 tl (f64)
            const int kk = tid >> 4;
            const int t4 = (tid & 15) * 4;
            const int f = k0 + kk;
            if (f < 500) {
                const size_t base = ((size_t)b * 500 + f) * TCG + t_off + tl0 + t4;
                const double2 v0 = *(const double2*)&A2[base];
                const double2 v1 = *(const double2*)&A2[base + 2];
                At[kk][t4+0] = v0.x; At[kk][t4+1] = v0.y;
                At[kk][t4+2] = v1.x; At[kk][t4+3] = v1.y;
            } else {
                At[kk][t4+0] = 0.0; At[kk][t4+1] = 0.0;
                At[kk][t4+2] = 0.0; At[kk][t4+3] = 0.0;
            }
        }
        {   // stage W: 16 f x 64 o (f32)
            const int oo = tid >> 2;
            const int fc = (tid & 3) * 4;
            int o = o0 + oo; if (o > 499) o = 499;
            const int f = k0 + fc;
            if (f + 3 < 500) {
                const float4 w = *(const float4*)&W2[(size_t)o * 500 + f];
                Wo[fc+0][oo] = w.x; Wo[fc+1][oo] = w.y;
                Wo[fc+2][oo] = w.z; Wo[fc+3][oo] = w.w;
            } else {
                #pragma unroll
                for (int c = 0; c < 4; ++c)
                    Wo[fc+c][oo] = (f + c < 500) ? W2[(size_t)o * 500 + f + c] : 0.0f;
            }
        }
        __syncthreads();
        #pragma unroll
        for (int ks = 0; ks < 4; ++ks) {
            const int kr = 4 * ks + lk;
            const double a0 = At[kr][wtl + lr];
            const double a1 = At[kr][wtl + 16 + lr];
            const double w0 = (double)Wo[kr][wo + lr];
            const double w1 = (double)Wo[kr][wo + 16 + lr];
            acc[0][0] = __builtin_amdgcn_mfma_f64_16x16x4f64(a0, w0, acc[0][0], 0, 0, 0);
            acc[0][1] = __builtin_amdgcn_mfma_f64_16x16x4f64(a0, w1, acc[0][1], 0, 0, 0);
            acc[1][0] = __builtin_amdgcn_mfma_f64_16x16x4f64(a1, w0, acc[1][0], 0, 0, 0);
            acc[1][1] = __builtin_amdgcn_mfma_f64_16x16x4f64(a1, w1, acc[1][1], 0, 0, 0);
        }
        __syncthreads();
    }

    const int flag = (int)FLG[0];
    for (int ti = 0; ti < 2; ++ti)
    for (int oj = 0; oj < 2; ++oj)
    for (int v = 0; v < 4; ++v) {
        int rl, cl;
        frag_rc(flag, lk, lr, v, rl, cl);
        const int tl = tl0 + wtl + ti * 16 + rl;
        const int o  = o0 + wo + oj * 16 + cl;
        if (o < 500)
            WX2[((size_t)tl * 64 + b) * 500 + o] = acc[ti][oj][v] + (double)B2[o];
    }
}

// ---------------------------------------------------------------------------
// LIF2 + IIR3 fused, in-place on (TCS, 32000); carries (v, sp, m, s).
// ---------------------------------------------------------------------------
__global__ __launch_bounds__(256) void lif2iir3_chunk(
    double* __restrict__ WX,
    double* __restrict__ stV, double* __restrict__ stSp,
    double* __restrict__ stM, double* __restrict__ stS, int first)
{
    const int idx = blockIdx.x * 256 + threadIdx.x;
    if (idx >= 32000) return;
    double v, sp, m, s;
    if (first) { v = 0.0; sp = 0.0; m = 0.0; s = 0.0; }
    else { v = stV[idx]; sp = stSp[idx]; m = stM[idx]; s = stS[idx]; }
    for (int tt = 0; tt < TCS; ++tt) {
        const double cur = WX[(size_t)tt * 32000 + idx];
        v = EMD * v * (1.0 - sp) + cur;
        sp = (v >= 1.0) ? 1.0 : 0.0;
        m = EMD * m + sp;
        s = ESD * s + sp;
        WX[(size_t)tt * 32000 + idx] = m - s;
    }
    stV[idx] = v; stSp[idx] = sp; stM[idx] = m; stS[idx] = s;
}

// ---------------------------------------------------------------------------
// g3: one wave per R; lanes split K, 10 outputs tree-reduced via shfl_xor.
// ---------------------------------------------------------------------------
__global__ __launch_bounds__(256) void g3_chunk(
    const double* __restrict__ A3,  // (64*TCS, 500)
    const float* __restrict__ W3,   // (10,500)
    const float* __restrict__ B3,   // (10)
    double* __restrict__ WX3)       // (64*TCS, 10)
{
    __shared__ float w3s[5000];
    for (int i = threadIdx.x; i < 5000; i += 256) w3s[i] = W3[i];
    __syncthreads();

    const int lane = threadIdx.x & 63;
    const int R = blockIdx.x * 4 + (threadIdx.x >> 6);   // 0..8191
    const double* row = A3 + (size_t)R * 500;

    double p[10] = {};
    #pragma unroll
    for (int c = 0; c < 8; ++c) {
        const int i = c * 64 + lane;
        const int ii = (i < 500) ? i : 0;
        const double x = (i < 500) ? row[ii] : 0.0;
        #pragma unroll
        for (int o = 0; o < 10; ++o)
            p[o] = fma(x, (double)w3s[o * 500 + ii], p[o]);
    }
    #pragma unroll
    for (int off = 32; off; off >>= 1)
        #pragma unroll
        for (int o = 0; o < 10; ++o)
            p[o] += __shfl_xor(p[o], off, 64);
    if (lane < 10)
        WX3[(size_t)R * 10 + lane] = p[lane] + (double)B3[lane];
}

// ---------------------------------------------------------------------------
// lif3: (tt*640+idx) -> OUT[idx*512 + t0+tt]; carries (v, sp).
// ---------------------------------------------------------------------------
__global__ __launch_bounds__(256) void lif3_chunk(
    const double* __restrict__ WX3, float* __restrict__ OUT,
    double* __restrict__ stV, double* __restrict__ stSp, int first, int t0)
{
    const int idx = blockIdx.x * 256 + threadIdx.x;
    if (idx >= 640) return;
    double v = first ? 0.0 : stV[idx];
    double sp = first ? 0.0 : stSp[idx];
    for (int tt = 0; tt < TCS; ++tt) {
        const double cur = WX3[(size_t)tt * 640 + idx];
        v = EMD * v * (1.0 - sp) + cur;
        sp = (v >= 1.0) ? 1.0 : 0.0;
        OUT[(size_t)idx * 512 + t0 + tt] = (float)sp;
    }
    stV[idx] = v; stSp[idx] = sp;
}

__global__ void sent_kernel(float* __restrict__ OUT, float v) { OUT[0] = v; }

// ---------------------------------------------------------------------------
extern "C" void kernel_launch(void* const* d_in, const int* in_sizes, int n_in,
                              void* d_out, int out_size, void* d_ws, size_t ws_size,
                              hipStream_t stream)
{
    float* OUT = (float*)d_out;

    const int expect[8] = {25690112, 16384000, 784000, 1000, 250000, 500, 5000, 10};
    int bad = -1;
    if (n_in != 8) bad = 0;
    else {
        for (int k = 0; k < 8; ++k)
            if (in_sizes[k] != expect[k]) { bad = 1 + k; break; }
        if (bad < 0 && out_size != 327680) bad = 9;
        if (bad < 0 && ws_size < (size_t)131072000) bad = 10;
    }
    if (bad >= 0) {
        sent_kernel<<<1, 1, 0, stream>>>(OUT, 4100.0f + bad);
        return;
    }

    const float* X   = (const float*)d_in[0];
    const float* EPS = (const float*)d_in[1];
    const float* W1  = (const float*)d_in[2];
    const float* B1  = (const float*)d_in[3];
    const float* W2  = (const float*)d_in[4];
    const float* B2  = (const float*)d_in[5];
    const float* W3  = (const float*)d_in[6];
    const float* B3  = (const float*)d_in[7];

    double* ws = (double*)d_ws;
    double* buf1  = ws;               // (64,500,TCG)  8,192,000 doubles
    double* buf2  = ws + 8192000;     // (TCS,64,500)  4,096,000
    double* buf4  = ws + 12288000;    // (64*TCS,10)      81,920
    double* stM2  = ws + 12400000;    // 32,000 each
    double* stS2  = ws + 12432000;
    double* stV2  = ws + 12464000;
    double* stSp2 = ws + 12496000;
    double* stM3  = ws + 12528000;
    double* stS3  = ws + 12560000;
    double* stV3  = ws + 12592000;    // 640 each
    double* stSp3 = ws + 12593000;
    double* FLG   = ws + 12600000;    // MFMA layout flag

    mfma_probe<<<1, 64, 0, stream>>>(FLG);

    for (int tc = 0; tc < 512 / TCG; ++tc) {
        const int t0 = tc * TCG;
        const int firstc = (tc == 0) ? 1 : 0;
        g1_mfma<<<dim3(TCG / 64, 8, 64), 256, 0, stream>>>(X, W1, B1, EPS, buf1, FLG, t0);
        iir2_chunk<<<500, 256, 0, stream>>>(buf1, stM2, stS2, firstc);
        for (int h = 0; h < TCG / TCS; ++h) {
            const int first = (firstc && h == 0) ? 1 : 0;
            g2_mfma<<<dim3(TCS / 64, 8, 64), 256, 0, stream>>>(buf1, W2, B2, buf2, FLG, h * TCS);
            lif2iir3_chunk<<<125, 256, 0, stream>>>(buf2, stV2, stSp2, stM3, stS3, first);
            g3_chunk<<<2048, 256, 0, stream>>>(buf2, W3, B3, buf4);
            lif3_chunk<<<3, 256, 0, stream>>>(buf4, OUT, stV3, stSp3, first, t0 + h * TCS);
        }
    }
}